// Round 14
// baseline (89.247 us; speedup 1.0000x reference)
//
#include <hip/hip_runtime.h>
#include <hip/hip_bf16.h>
#include <cstdint>

#define LQ 1024
#define LK 1024
#define DD 512
#define NB 16
#define QB 64
#define KB 32
#define NT (LK / KB)
#define CSTRIDE 1088  // 1024 + 64: linear-in-s S^T reads with 8-quad bank spread
#define CSZ (32 * CSTRIDE)

typedef short bf16x8 __attribute__((ext_vector_type(8)));
typedef float f32x4 __attribute__((ext_vector_type(4)));

__device__ __forceinline__ uint16_t f2bf(float f) {
  uint32_t u = __builtin_bit_cast(uint32_t, f);
  u = (u + 0x7fffu + ((u >> 16) & 1u)) >> 16;  // RNE; inputs finite
  return (uint16_t)u;
}

__device__ __forceinline__ void load_lds16(const void* g, void* l) {
  __builtin_amdgcn_global_load_lds(
      (const __attribute__((address_space(1))) uint32_t*)g,
      (__attribute__((address_space(3))) uint32_t*)l, 16, 0, 0);
}

// ---------- fused prepass: C fp32 -> Cb bf16 [B][Lk][D] + Ct bf16 [B][D][Lk] ----------
__global__ __launch_bounds__(256) void prep_kernel(const float* __restrict__ c,
                                                   uint16_t* __restrict__ cb,
                                                   uint16_t* __restrict__ ct) {
  __shared__ float t[32][33];
  const int k0 = blockIdx.x * 32, d0 = blockIdx.y * 32, b = blockIdx.z;
  const float* src = c + (size_t)b * LK * DD;
  uint16_t* cbd = cb + (size_t)b * LK * DD;
  uint16_t* ctd = ct + (size_t)b * DD * LK;
  const int tx = threadIdx.x, ty = threadIdx.y;
  for (int j = 0; j < 4; ++j) {
    int k = ty + j * 8;
    float v = src[(size_t)(k0 + k) * DD + d0 + tx];
    t[k][tx] = v;
    cbd[(size_t)(k0 + k) * DD + d0 + tx] = f2bf(v);
  }
  __syncthreads();
  for (int j = 0; j < 4; ++j) {
    int d = ty + j * 8;
    ctd[(size_t)(d0 + d) * LK + k0 + tx] = f2bf(t[tx][d]);
  }
}

// ---------------- fused attention + residual + LayerNorm ----------------
// grid = 256, block = 512 (8 waves). ROLE SPLIT on r13's rhythm:
//   waves 0-3 PRODUCERS: each computes TWO S^T tiles sharing the A-fragments
//     (same mt, qt and qt+2) -> S^T A-reads 128 -> 64 per iter. Writes P.
//   waves 4-7 CONSUMERS: each owns a 128-wide d-slice; PV from LDS (pa 16,
//     pb 32 reads/iter). oacc[4][8].
// Separate loops per role so qfrag (128 VGPR, producer) and oacc (128 VGPR,
// consumer) never union (r7's spill trap). All LDS data staged 1 iter ahead.
// Barriers per iter: mid s_barrier (P visible) + end __syncthreads (drain).
__global__ __launch_bounds__(512, 2) void attn_kernel(
    const uint16_t* __restrict__ Cb, const uint16_t* __restrict__ Ctb,
    const float* __restrict__ Qf, const float* __restrict__ gamma,
    const float* __restrict__ beta, float* __restrict__ out) {
  __shared__ uint4 cs4[2 * CSZ / 16];         // 2 x 34 KB C tile [32 kk][512 d]
  __shared__ uint4 cts4[2 * 32 * 1024 / 16];  // 2 x 32 KB Ct tile [512 d][32 kk]
  __shared__ char plds[64 * 80];              // 5 KB P [64 q][32 kk], stride 80
  __shared__ float denom_s[QB];
  __shared__ float rsum_s[QB], rsumsq_s[QB], mean_s[QB], rstd_s[QB];

  const int tid = threadIdx.x;
  const int w = tid >> 6, l = tid & 63, c = l & 15, g = l >> 4;
  const int orig = blockIdx.x;
  const int virt = ((orig & 7) << 5) | (orig >> 3);  // 256 % 8 == 0: bijective
  const int b = virt >> 4, qblk = virt & 15;
  const int q0 = qblk * QB;
  const float scale = 0.044194173824159216f;  // 1/sqrt(512)

  if (tid < QB) { denom_s[tid] = 0.f; rsum_s[tid] = 0.f; rsumsq_s[tid] = 0.f; }

  const char* cbyte = (const char*)Cb + (size_t)b * LK * DD * 2;
  const char* ctbyte = (const char*)Ctb + (size_t)b * DD * LK * 2;
  char* cs0 = (char*)cs4;
  char* cs1 = cs0 + CSZ;
  char* cts0 = (char*)cts4;
  char* cts1 = cts0 + 32 * 1024;
  const int proff = c * 80 + g * 16;

  // prologue staging of tile 0 (all 8 waves, r13 split: 4+4 ops each)
  {
    for (int j = 0; j < 4; ++j) {
      int r = w * 4 + j;
      load_lds16(cbyte + r * 1024 + ((l * 16) ^ ((r & 3) << 4)),
                 cs0 + r * CSTRIDE);
    }
    for (int j = 0; j < 4; ++j) {
      int d0l = w * 64 + j * 16;
      int d = d0l + (l >> 2);
      load_lds16(ctbyte + (size_t)d * 2048 + (((l & 3) * 16) ^ ((d & 3) << 4)),
                 cts0 + d0l * 64);
    }
  }
  __syncthreads();  // tile 0 staged; zero-inits visible

  if (w < 4) {
    // ===================== PRODUCERS (2 S^T tiles, shared A) =====================
    const int mt = w & 1, qa = w >> 1, qb2 = qa + 2;
    bf16x8 qfA[16], qfB[16];
    {
      const float* ra = Qf + ((size_t)b * LQ + q0 + qa * 16 + c) * DD;
      const float* rb = Qf + ((size_t)b * LQ + q0 + qb2 * 16 + c) * DD;
      for (int s = 0; s < 16; ++s) {
        float4 a0 = *(const float4*)(ra + s * 32 + g * 8);
        float4 a1 = *(const float4*)(ra + s * 32 + g * 8 + 4);
        ushort4 u0, u1;
        u0.x = f2bf(a0.x); u0.y = f2bf(a0.y); u0.z = f2bf(a0.z); u0.w = f2bf(a0.w);
        u1.x = f2bf(a1.x); u1.y = f2bf(a1.y); u1.z = f2bf(a1.z); u1.w = f2bf(a1.w);
        union { ushort4 u[2]; bf16x8 v; } pk;
        pk.u[0] = u0; pk.u[1] = u1;
        qfA[s] = pk.v;
        float4 b0 = *(const float4*)(rb + s * 32 + g * 8);
        float4 b1 = *(const float4*)(rb + s * 32 + g * 8 + 4);
        ushort4 v0, v1;
        v0.x = f2bf(b0.x); v0.y = f2bf(b0.y); v0.z = f2bf(b0.z); v0.w = f2bf(b0.w);
        v1.x = f2bf(b1.x); v1.y = f2bf(b1.y); v1.z = f2bf(b1.z); v1.w = f2bf(b1.w);
        union { ushort4 u[2]; bf16x8 v; } pk2;
        pk2.u[0] = v0; pk2.u[1] = v1;
        qfB[s] = pk2.v;
      }
    }
    const int kkA = mt * 16 + c;
    const int aoff = kkA * CSTRIDE + ((g ^ (kkA & 3)) * 16);
    int csoff[8];
    for (int j = 0; j < 8; ++j) {
      int r = w * 8 + j;
      csoff[j] = r * 1024 + ((l * 16) ^ ((r & 3) << 4));
    }
    const int pwA = (qa * 16 + c) * 80 + (mt * 16 + g * 4) * 2;
    const int pwB = (qb2 * 16 + c) * 80 + (mt * 16 + g * 4) * 2;
    float dA = 0.f, dB = 0.f;

    for (int kt = 0; kt < NT; ++kt) {
      const int cur = kt & 1;
      if (kt + 1 < NT) {  // producers stage all of cs(kt+1): 4 waves x 8 rows
        const char* s0 = cbyte + (size_t)(kt + 1) * 32768;
        char* dst = cur ? cs0 : cs1;
        for (int j = 0; j < 8; ++j)
          load_lds16(s0 + csoff[j], dst + (w * 8 + j) * CSTRIDE);
      }
      // S^T both tiles: 16 A-reads feed 32 MFMAs (A shared)
      f32x4 sA0 = {0,0,0,0}, sA1 = {0,0,0,0}, sA2 = {0,0,0,0}, sA3 = {0,0,0,0};
      f32x4 sB0 = {0,0,0,0}, sB1 = {0,0,0,0}, sB2 = {0,0,0,0}, sB3 = {0,0,0,0};
      {
        const char* ar = (cur ? cs1 : cs0) + aoff;
        for (int s = 0; s < 4; ++s) {
          bf16x8 a0 = *(const bf16x8*)(ar + s * 64);
          bf16x8 a1 = *(const bf16x8*)(ar + (s + 4) * 64);
          bf16x8 a2 = *(const bf16x8*)(ar + (s + 8) * 64);
          bf16x8 a3 = *(const bf16x8*)(ar + (s + 12) * 64);
          sA0 = __builtin_amdgcn_mfma_f32_16x16x32_bf16(a0, qfA[s], sA0, 0, 0, 0);
          sB0 = __builtin_amdgcn_mfma_f32_16x16x32_bf16(a0, qfB[s], sB0, 0, 0, 0);
          sA1 = __builtin_amdgcn_mfma_f32_16x16x32_bf16(a1, qfA[s + 4], sA1, 0, 0, 0);
          sB1 = __builtin_amdgcn_mfma_f32_16x16x32_bf16(a1, qfB[s + 4], sB1, 0, 0, 0);
          sA2 = __builtin_amdgcn_mfma_f32_16x16x32_bf16(a2, qfA[s + 8], sA2, 0, 0, 0);
          sB2 = __builtin_amdgcn_mfma_f32_16x16x32_bf16(a2, qfB[s + 8], sB2, 0, 0, 0);
          sA3 = __builtin_amdgcn_mfma_f32_16x16x32_bf16(a3, qfA[s + 12], sA3, 0, 0, 0);
          sB3 = __builtin_amdgcn_mfma_f32_16x16x32_bf16(a3, qfB[s + 12], sB3, 0, 0, 0);
        }
      }
      // P = exp(tanh(s*scale)) for both tiles
      {
        float pvA[4], pvB[4];
        for (int i = 0; i < 4; ++i) {
          float sv = ((sA0[i] + sA1[i]) + (sA2[i] + sA3[i])) * scale;
          float e2 = __expf(sv * 2.f);
          float th = (e2 - 1.f) * __builtin_amdgcn_rcpf(e2 + 1.f);
          float p = __expf(th);
          pvA[i] = p;
          dA += p;
          float sw = ((sB0[i] + sB1[i]) + (sB2[i] + sB3[i])) * scale;
          float f2 = __expf(sw * 2.f);
          float tg = (f2 - 1.f) * __builtin_amdgcn_rcpf(f2 + 1.f);
          float q = __expf(tg);
          pvB[i] = q;
          dB += q;
        }
        uint2 ka, kb;
        asm("v_cvt_pk_bf16_f32 %0, %1, %2" : "=v"(ka.x) : "v"(pvA[0]), "v"(pvA[1]));
        asm("v_cvt_pk_bf16_f32 %0, %1, %2" : "=v"(ka.y) : "v"(pvA[2]), "v"(pvA[3]));
        asm("v_cvt_pk_bf16_f32 %0, %1, %2" : "=v"(kb.x) : "v"(pvB[0]), "v"(pvB[1]));
        asm("v_cvt_pk_bf16_f32 %0, %1, %2" : "=v"(kb.y) : "v"(pvB[2]), "v"(pvB[3]));
        *(uint2*)(plds + pwA) = ka;
        *(uint2*)(plds + pwB) = kb;
      }
      // mid barrier: P visible (DS drained); staging stays in flight
      asm volatile("s_waitcnt lgkmcnt(0)" ::: "memory");
      __builtin_amdgcn_s_barrier();
      __builtin_amdgcn_sched_barrier(0);
      __syncthreads();  // end barrier: full drain
    }
    // denom: per tile reduce over g, combine mt halves via atomics
    float dv = dA;
    dv += __shfl_xor(dv, 16);
    dv += __shfl_xor(dv, 32);
    if (l < 16) atomicAdd(&denom_s[qa * 16 + l], dv);
    float dw = dB;
    dw += __shfl_xor(dw, 16);
    dw += __shfl_xor(dw, 32);
    if (l < 16) atomicAdd(&denom_s[qb2 * 16 + l], dw);
    __syncthreads();  // denom complete
    __syncthreads();  // match consumers' LN-partials barrier
    if (tid < QB) {
      float m = rsum_s[tid] * (1.f / DD);
      float var = rsumsq_s[tid] * (1.f / DD) - m * m;
      mean_s[tid] = m;
      rstd_s[tid] = rsqrtf(fmaxf(var, 0.f) + 1e-6f);
    }
    __syncthreads();  // stats ready
  } else {
    // ===================== CONSUMERS (PV over d-slice 128) =====================
    const int cw = w - 4;
    f32x4 oacc[4][8];
    for (int i = 0; i < 4; ++i)
      for (int j = 0; j < 8; ++j) oacc[i][j] = (f32x4){0.f, 0.f, 0.f, 0.f};
    int ctsrc[8], ctdst[8], pboff[8];
    for (int j = 0; j < 8; ++j) {
      int d0l = cw * 128 + j * 16;
      int d = d0l + (l >> 2);
      ctsrc[j] = d * 2048 + (((l & 3) * 16) ^ ((d & 3) << 4));
      ctdst[j] = d0l * 64;
      int dp = cw * 128 + j * 16 + c;
      pboff[j] = dp * 64 + ((g * 16) ^ ((dp & 3) << 4));
    }

    for (int kt = 0; kt < NT; ++kt) {
      const int cur = kt & 1;
      const char* ctsR = cur ? cts1 : cts0;
      if (kt + 1 < NT) {  // consumers stage all of cts(kt+1): 4 waves x 8 ops
        const int kk0 = (kt + 1) * KB;
        char* dst = cur ? cts0 : cts1;
        for (int j = 0; j < 8; ++j)
          load_lds16(ctbyte + (size_t)ctsrc[j] + kk0 * 2, dst + ctdst[j]);
      }
      bf16x8 pb[8];
      for (int nt = 0; nt < 8; ++nt)
        pb[nt] = *(const bf16x8*)(ctsR + pboff[nt]);
      __builtin_amdgcn_s_barrier();  // mid barrier: P(kt) now visible
      __builtin_amdgcn_sched_barrier(0);
      {
        bf16x8 pa[4];
        for (int q2 = 0; q2 < 4; ++q2)
          pa[q2] = *(const bf16x8*)(plds + proff + q2 * 1280);
        for (int q2 = 0; q2 < 4; ++q2)
          for (int n2 = 0; n2 < 8; ++n2)
            oacc[q2][n2] =
                __builtin_amdgcn_mfma_f32_16x16x32_bf16(pa[q2], pb[n2], oacc[q2][n2], 0, 0, 0);
      }
      __syncthreads();  // end barrier: full drain
    }
    __syncthreads();  // denom complete

    // epilogue: y = O/denom + query (fp32), LN partials
    const float* qsrc = Qf + ((size_t)b * LQ + q0) * DD;
    for (int q2 = 0; q2 < 4; ++q2)
      for (int i = 0; i < 4; ++i) {
        int row = q2 * 16 + g * 4 + i;
        float inv = 1.f / denom_s[row];
        for (int nt = 0; nt < 8; ++nt) {
          int d = cw * 128 + nt * 16 + c;
          float o = oacc[q2][nt][i] * inv + qsrc[(size_t)row * DD + d];
          oacc[q2][nt][i] = o;
        }
      }
    for (int q2 = 0; q2 < 4; ++q2)
      for (int i = 0; i < 4; ++i) {
        float s1 = 0.f, s2 = 0.f;
        for (int nt = 0; nt < 8; ++nt) {
          float v = oacc[q2][nt][i];
          s1 += v;
          s2 += v * v;
        }
        s1 += __shfl_xor(s1, 1); s2 += __shfl_xor(s2, 1);
        s1 += __shfl_xor(s1, 2); s2 += __shfl_xor(s2, 2);
        s1 += __shfl_xor(s1, 4); s2 += __shfl_xor(s2, 4);
        s1 += __shfl_xor(s1, 8); s2 += __shfl_xor(s2, 8);
        if (c == 0) {
          int row = q2 * 16 + g * 4 + i;
          atomicAdd(&rsum_s[row], s1);
          atomicAdd(&rsumsq_s[row], s2);
        }
      }
    __syncthreads();  // partials done (producers compute stats)
    __syncthreads();  // stats ready
    float* op = out + ((size_t)b * LQ + q0) * DD;
    for (int q2 = 0; q2 < 4; ++q2)
      for (int i = 0; i < 4; ++i) {
        int row = q2 * 16 + g * 4 + i;
        float m = mean_s[row], r = rstd_s[row];
        for (int nt = 0; nt < 8; ++nt) {
          int d = cw * 128 + nt * 16 + c;
          op[(size_t)row * DD + d] = gamma[d] * ((oacc[q2][nt][i] - m) * r) + beta[d];
        }
      }
  }
}

// ---------------- slow-but-correct fallback (if ws too small) ----------------
__global__ __launch_bounds__(256) void naive_kernel(const float* __restrict__ Q,
                                                    const float* __restrict__ C,
                                                    const float* __restrict__ gamma,
                                                    const float* __restrict__ beta,
                                                    float* __restrict__ out) {
  const int row = blockIdx.x;
  const int b = row >> 10;
  const int tid = threadIdx.x;
  __shared__ float qs[DD];
  __shared__ float ps[LK];
  __shared__ float ys[DD];
  __shared__ float red[256];
  const float* qp = Q + (size_t)row * DD;
  const float* cb = C + (size_t)b * LK * DD;
  for (int d = tid; d < DD; d += 256) qs[d] = qp[d];
  __syncthreads();
  for (int k = tid; k < LK; k += 256) {
    const float* cr = cb + (size_t)k * DD;
    float s = 0.f;
    for (int d = 0; d < DD; ++d) s += qs[d] * cr[d];
    s *= 0.044194173824159216f;
    float e2 = __expf(2.f * s);
    float th = (e2 - 1.f) / (e2 + 1.f);
    ps[k] = __expf(th);
  }
  __syncthreads();
  float dsum = 0.f;
  for (int k = tid; k < LK; k += 256) dsum += ps[k];
  red[tid] = dsum;
  __syncthreads();
  for (int off = 128; off; off >>= 1) {
    if (tid < off) red[tid] += red[tid + off];
    __syncthreads();
  }
  float inv = 1.f / red[0];
  __syncthreads();
  for (int d = tid; d < DD; d += 256) {
    float o = 0.f;
    for (int k = 0; k < LK; ++k) o += ps[k] * cb[(size_t)k * DD + d];
    ys[d] = o * inv + qs[d];
  }
  __syncthreads();
  float s1 = 0.f;
  for (int d = tid; d < DD; d += 256) s1 += ys[d];
  red[tid] = s1;
  __syncthreads();
  for (int off = 128; off; off >>= 1) {
    if (tid < off) red[tid] += red[tid + off];
    __syncthreads();
  }
  float mean = red[0] * (1.f / DD);
  __syncthreads();
  float s2 = 0.f;
  for (int d = tid; d < DD; d += 256) {
    float v = ys[d] - mean;
    s2 += v * v;
  }
  red[tid] = s2;
  __syncthreads();
  for (int off = 128; off; off >>= 1) {
    if (tid < off) red[tid] += red[tid + off];
    __syncthreads();
  }
  float rstd = rsqrtf(red[0] * (1.f / DD) + 1e-6f);
  for (int d = tid; d < DD; d += 256)
    out[(size_t)row * DD + d] = gamma[d] * ((ys[d] - mean) * rstd) + beta[d];
}

extern "C" void kernel_launch(void* const* d_in, const int* in_sizes, int n_in,
                              void* d_out, int out_size, void* d_ws, size_t ws_size,
                              hipStream_t stream) {
  const float* Qf = (const float*)d_in[0];
  const float* Cf = (const float*)d_in[1];
  const float* gamma = (const float*)d_in[2];
  const float* beta = (const float*)d_in[3];
  float* out = (float*)d_out;
  const size_t nelem = (size_t)NB * LK * DD;  // 8,388,608
  const size_t need = nelem * 2 * 2;          // Cb + Ctb (33.5 MB)
  if (ws_size >= need) {
    uint16_t* Cb = (uint16_t*)d_ws;
    uint16_t* Ctb = Cb + nelem;
    prep_kernel<<<dim3(LK / 32, DD / 32, NB), dim3(32, 8), 0, stream>>>(Cf, Cb, Ctb);
    attn_kernel<<<256, 512, 0, stream>>>(Cb, Ctb, Qf, gamma, beta, out);
  } else {
    naive_kernel<<<NB * LQ, 256, 0, stream>>>(Qf, Cf, gamma, beta, out);
  }
}

// Round 15
// 82.212 us; speedup vs baseline: 1.0856x; 1.0856x over previous
//
#include <hip/hip_runtime.h>
#include <hip/hip_bf16.h>
#include <cstdint>

#define LQ 1024
#define LK 1024
#define DD 512
#define NB 16
#define QB 64
#define KB 32
#define NT (LK / KB)
#define CSTRIDE 1088  // 1024 + 64: linear-in-s S^T reads with 8-quad bank spread
#define CSZ (32 * CSTRIDE)

typedef short bf16x8 __attribute__((ext_vector_type(8)));
typedef float f32x4 __attribute__((ext_vector_type(4)));

__device__ __forceinline__ uint16_t f2bf(float f) {
  uint32_t u = __builtin_bit_cast(uint32_t, f);
  u = (u + 0x7fffu + ((u >> 16) & 1u)) >> 16;  // RNE; inputs finite
  return (uint16_t)u;
}

__device__ __forceinline__ void load_lds16(const void* g, void* l) {
  __builtin_amdgcn_global_load_lds(
      (const __attribute__((address_space(1))) uint32_t*)g,
      (__attribute__((address_space(3))) uint32_t*)l, 16, 0, 0);
}

// ---------- fused prepass: C fp32 -> Cb bf16 [B][Lk][D] + Ct bf16 [B][D][Lk] ----------
__global__ __launch_bounds__(256) void prep_kernel(const float* __restrict__ c,
                                                   uint16_t* __restrict__ cb,
                                                   uint16_t* __restrict__ ct) {
  __shared__ float t[32][33];
  const int k0 = blockIdx.x * 32, d0 = blockIdx.y * 32, b = blockIdx.z;
  const float* src = c + (size_t)b * LK * DD;
  uint16_t* cbd = cb + (size_t)b * LK * DD;
  uint16_t* ctd = ct + (size_t)b * DD * LK;
  const int tx = threadIdx.x, ty = threadIdx.y;
  for (int j = 0; j < 4; ++j) {
    int k = ty + j * 8;
    float v = src[(size_t)(k0 + k) * DD + d0 + tx];
    t[k][tx] = v;
    cbd[(size_t)(k0 + k) * DD + d0 + tx] = f2bf(v);
  }
  __syncthreads();
  for (int j = 0; j < 4; ++j) {
    int d = ty + j * 8;
    ctd[(size_t)(d0 + d) * LK + k0 + tx] = f2bf(t[tx][d]);
  }
}

// ---------------- fused attention + residual + LayerNorm ----------------
// grid = 256 (B=16 x 16 q-blocks of 64 rows), block = 512 (8 waves).
// FINAL (= round-13 champion, 82.3 us total / ~76 us attn):
//   r9 structure + v_cvt_pk_bf16_f32 P-pack. 14-round ledger: all structural
//   alternatives (pipeline lag, triple-buffer, QB=32, wave-spec, register-pb,
//   single-buffer, role-split) regressed; LDS pipe (~3.6k cyc of 4.5k/iter:
//   192 b128-class reads + DMA + b128 data-phase serialization) is the floor
//   of this structure at 1 block/CU.
// Rhythm: stage(kt+1) async -> S^T(kt) -> P(kt) -> lgkm+s_barrier -> PV(kt)
//         -> __syncthreads (full drain; staging had the whole iter in flight)
__global__ __launch_bounds__(512, 2) void attn_kernel(
    const uint16_t* __restrict__ Cb, const uint16_t* __restrict__ Ctb,
    const float* __restrict__ Qf, const float* __restrict__ gamma,
    const float* __restrict__ beta, float* __restrict__ out) {
  __shared__ uint4 cs4[2 * CSZ / 16];         // 2 x 34 KB C tile [32 kk][512 d]
  __shared__ uint4 cts4[2 * 32 * 1024 / 16];  // 2 x 32 KB Ct tile [512 d][32 kk]
  __shared__ char plds[64 * 80];              // 5 KB P [64 q][32 kk], stride 80
  __shared__ float denom_s[QB];
  __shared__ float rsum_s[QB], rsumsq_s[QB], mean_s[QB], rstd_s[QB];

  const int tid = threadIdx.x;
  const int w = tid >> 6, l = tid & 63, c = l & 15, g = l >> 4;
  const int orig = blockIdx.x;
  const int virt = ((orig & 7) << 5) | (orig >> 3);  // 256 % 8 == 0: bijective
  const int b = virt >> 4, qblk = virt & 15;
  const int q0 = qblk * QB;
  const int mt = w & 1, qt = w >> 1;
  const float scale = 0.044194173824159216f;  // 1/sqrt(512)

  if (tid < QB) { denom_s[tid] = 0.f; rsum_s[tid] = 0.f; rsumsq_s[tid] = 0.f; }

  // Q fragments (B operand of S^T) from fp32, converted in-register
  bf16x8 qfrag[16];
  {
    const float* qrow = Qf + ((size_t)b * LQ + q0 + qt * 16 + c) * DD;
    for (int s = 0; s < 16; ++s) {
      float4 a0 = *(const float4*)(qrow + s * 32 + g * 8);
      float4 a1 = *(const float4*)(qrow + s * 32 + g * 8 + 4);
      ushort4 u0, u1;
      u0.x = f2bf(a0.x); u0.y = f2bf(a0.y); u0.z = f2bf(a0.z); u0.w = f2bf(a0.w);
      u1.x = f2bf(a1.x); u1.y = f2bf(a1.y); u1.z = f2bf(a1.z); u1.w = f2bf(a1.w);
      union { ushort4 u[2]; bf16x8 v; } pk;
      pk.u[0] = u0; pk.u[1] = u1;
      qfrag[s] = pk.v;
    }
  }

  const int kkA = mt * 16 + c;
  const int aoff = kkA * CSTRIDE + ((g ^ (kkA & 3)) * 16);

  f32x4 oacc[4][4];
  for (int i = 0; i < 4; ++i)
    for (int j = 0; j < 4; ++j) oacc[i][j] = (f32x4){0.f, 0.f, 0.f, 0.f};
  float dacc = 0.f;

  const char* cbyte = (const char*)Cb + (size_t)b * LK * DD * 2;
  const char* ctbyte = (const char*)Ctb + (size_t)b * DD * LK * 2;

  // staging source offsets (source pre-swizzled; LDS dest linear per DMA rule)
  int csrcoff[4];
  for (int j = 0; j < 4; ++j) {
    int r = w * 4 + j;
    csrcoff[j] = r * 1024 + ((l * 16) ^ ((r & 3) << 4));
  }

  char* cs0 = (char*)cs4;
  char* cs1 = cs0 + CSZ;
  char* cts0 = (char*)cts4;
  char* cts1 = cts0 + 32 * 1024;
  const int pwoff = (qt * 16 + c) * 80 + (mt * 16 + g * 4) * 2;
  const int proff = c * 80 + g * 16;

  auto stageC = [&](char* dst, int kt2) {
    const char* s0 = cbyte + (size_t)kt2 * 32768;
    for (int j = 0; j < 4; ++j)
      load_lds16(s0 + csrcoff[j], dst + (w * 4 + j) * CSTRIDE);
  };
  auto stageCT = [&](char* dst, int kt2) {
    const int kk0 = kt2 * KB;
    for (int j = 0; j < 4; ++j) {  // wave w -> d rows w*64 .. w*64+63, 16/issue
      int d0l = w * 64 + j * 16;
      int d = d0l + (l >> 2);
      const char* src =
          ctbyte + (size_t)d * 2048 + kk0 * 2 + (((l & 3) * 16) ^ ((d & 3) << 4));
      load_lds16(src, dst + d0l * 64);
    }
  };

  stageC(cs0, 0);
  stageCT(cts0, 0);
  __syncthreads();  // prologue drain; zero-inits visible

  for (int kt = 0; kt < NT; ++kt) {
    const int cur = kt & 1;
    const char* csR = cur ? cs1 : cs0;
    const char* ctsR = cur ? cts1 : cts0;
    if (kt + 1 < NT) {  // async staging, in flight across the mid barrier
      stageC(cur ? cs0 : cs1, kt + 1);
      stageCT(cur ? cts0 : cts1, kt + 1);
    }
    // S^T(kt): lane (c,g) -> kk=mt*16+g*4+i, q=qt*16+c; 4 independent chains
    f32x4 s0v = {0.f, 0.f, 0.f, 0.f}, s1v = {0.f, 0.f, 0.f, 0.f};
    f32x4 s2v = {0.f, 0.f, 0.f, 0.f}, s3v = {0.f, 0.f, 0.f, 0.f};
    {
      const char* ar = csR + aoff;
      for (int s = 0; s < 4; ++s) {
        bf16x8 a0 = *(const bf16x8*)(ar + s * 64);
        bf16x8 a1 = *(const bf16x8*)(ar + (s + 4) * 64);
        bf16x8 a2 = *(const bf16x8*)(ar + (s + 8) * 64);
        bf16x8 a3 = *(const bf16x8*)(ar + (s + 12) * 64);
        s0v = __builtin_amdgcn_mfma_f32_16x16x32_bf16(a0, qfrag[s], s0v, 0, 0, 0);
        s1v = __builtin_amdgcn_mfma_f32_16x16x32_bf16(a1, qfrag[s + 4], s1v, 0, 0, 0);
        s2v = __builtin_amdgcn_mfma_f32_16x16x32_bf16(a2, qfrag[s + 8], s2v, 0, 0, 0);
        s3v = __builtin_amdgcn_mfma_f32_16x16x32_bf16(a3, qfrag[s + 12], s3v, 0, 0, 0);
      }
    }
    // P(kt) = exp(tanh(s*scale)) in [e^-1, e^1] -> no max tracking
    {
      float pv[4];
      for (int i = 0; i < 4; ++i) {
        float sv = ((s0v[i] + s1v[i]) + (s2v[i] + s3v[i])) * scale;
        float e2 = __expf(sv * 2.f);
        float r = __builtin_amdgcn_rcpf(e2 + 1.f);
        float th = (e2 - 1.f) * r;
        float p = __expf(th);
        pv[i] = p;
        dacc += p;
      }
      uint2 pk;
      asm("v_cvt_pk_bf16_f32 %0, %1, %2" : "=v"(pk.x) : "v"(pv[0]), "v"(pv[1]));
      asm("v_cvt_pk_bf16_f32 %0, %1, %2" : "=v"(pk.y) : "v"(pv[2]), "v"(pv[3]));
      *(uint2*)(plds + pwoff) = pk;
    }
    // mid barrier: P + this tile's reads done (DS only); staging stays in flight
    asm volatile("s_waitcnt lgkmcnt(0)" ::: "memory");
    __builtin_amdgcn_s_barrier();
    __builtin_amdgcn_sched_barrier(0);

    // PV(kt): O[q][d] += P[q][kk] * C[kk][d]; wave w owns d in [w*64, w*64+64)
    {
      bf16x8 pa[4], pb[4];
      for (int q2 = 0; q2 < 4; ++q2)
        pa[q2] = *(const bf16x8*)(plds + proff + q2 * 1280);
      for (int nt = 0; nt < 4; ++nt) {
        int d = w * 64 + nt * 16 + c;
        pb[nt] = *(const bf16x8*)(ctsR + d * 64 + ((g * 16) ^ ((d & 3) << 4)));
      }
      for (int q2 = 0; q2 < 4; ++q2)
        for (int n2 = 0; n2 < 4; ++n2)
          oacc[q2][n2] =
              __builtin_amdgcn_mfma_f32_16x16x32_bf16(pa[q2], pb[n2], oacc[q2][n2], 0, 0, 0);
    }
    __syncthreads();  // end barrier: next tile staged (full drain) + P reads done
  }

  // denom: reduce over g (shfl 16,32), combine mt-halves via LDS atomics
  float dv = dacc;
  dv += __shfl_xor(dv, 16);
  dv += __shfl_xor(dv, 32);
  if (l < 16) atomicAdd(&denom_s[qt * 16 + l], dv);
  __syncthreads();

  // epilogue: y = O/denom + query (fp32), then LayerNorm over D
  const float* qsrc = Qf + ((size_t)b * LQ + q0) * DD;
  for (int q2 = 0; q2 < 4; ++q2)
    for (int i = 0; i < 4; ++i) {
      int row = q2 * 16 + g * 4 + i;
      float inv = 1.f / denom_s[row];
      for (int nt = 0; nt < 4; ++nt) {
        int d = w * 64 + nt * 16 + c;
        float o = oacc[q2][nt][i] * inv + qsrc[(size_t)row * DD + d];
        oacc[q2][nt][i] = o;
      }
    }
  for (int q2 = 0; q2 < 4; ++q2)
    for (int i = 0; i < 4; ++i) {
      float s1 = 0.f, s2 = 0.f;
      for (int nt = 0; nt < 4; ++nt) {
        float v = oacc[q2][nt][i];
        s1 += v;
        s2 += v * v;
      }
      s1 += __shfl_xor(s1, 1); s2 += __shfl_xor(s2, 1);
      s1 += __shfl_xor(s1, 2); s2 += __shfl_xor(s2, 2);
      s1 += __shfl_xor(s1, 4); s2 += __shfl_xor(s2, 4);
      s1 += __shfl_xor(s1, 8); s2 += __shfl_xor(s2, 8);
      if (c == 0) {
        int row = q2 * 16 + g * 4 + i;
        atomicAdd(&rsum_s[row], s1);
        atomicAdd(&rsumsq_s[row], s2);
      }
    }
  __syncthreads();
  if (tid < QB) {
    float m = rsum_s[tid] * (1.f / DD);
    float var = rsumsq_s[tid] * (1.f / DD) - m * m;
    mean_s[tid] = m;
    rstd_s[tid] = rsqrtf(fmaxf(var, 0.f) + 1e-6f);
  }
  __syncthreads();
  float* op = out + ((size_t)b * LQ + q0) * DD;
  for (int q2 = 0; q2 < 4; ++q2)
    for (int i = 0; i < 4; ++i) {
      int row = q2 * 16 + g * 4 + i;
      float m = mean_s[row], r = rstd_s[row];
      for (int nt = 0; nt < 4; ++nt) {
        int d = w * 64 + nt * 16 + c;
        op[(size_t)row * DD + d] = gamma[d] * ((oacc[q2][nt][i] - m) * r) + beta[d];
      }
    }
}

// ---------------- slow-but-correct fallback (if ws too small) ----------------
__global__ __launch_bounds__(256) void naive_kernel(const float* __restrict__ Q,
                                                    const float* __restrict__ C,
                                                    const float* __restrict__ gamma,
                                                    const float* __restrict__ beta,
                                                    float* __restrict__ out) {
  const int row = blockIdx.x;
  const int b = row >> 10;
  const int tid = threadIdx.x;
  __shared__ float qs[DD];
  __shared__ float ps[LK];
  __shared__ float ys[DD];
  __shared__ float red[256];
  const float* qp = Q + (size_t)row * DD;
  const float* cb = C + (size_t)b * LK * DD;
  for (int d = tid; d < DD; d += 256) qs[d] = qp[d];
  __syncthreads();
  for (int k = tid; k < LK; k += 256) {
    const float* cr = cb + (size_t)k * DD;
    float s = 0.f;
    for (int d = 0; d < DD; ++d) s += qs[d] * cr[d];
    s *= 0.044194173824159216f;
    float e2 = __expf(2.f * s);
    float th = (e2 - 1.f) / (e2 + 1.f);
    ps[k] = __expf(th);
  }
  __syncthreads();
  float dsum = 0.f;
  for (int k = tid; k < LK; k += 256) dsum += ps[k];
  red[tid] = dsum;
  __syncthreads();
  for (int off = 128; off; off >>= 1) {
    if (tid < off) red[tid] += red[tid + off];
    __syncthreads();
  }
  float inv = 1.f / red[0];
  __syncthreads();
  for (int d = tid; d < DD; d += 256) {
    float o = 0.f;
    for (int k = 0; k < LK; ++k) o += ps[k] * cb[(size_t)k * DD + d];
    ys[d] = o * inv + qs[d];
  }
  __syncthreads();
  float s1 = 0.f;
  for (int d = tid; d < DD; d += 256) s1 += ys[d];
  red[tid] = s1;
  __syncthreads();
  for (int off = 128; off; off >>= 1) {
    if (tid < off) red[tid] += red[tid + off];
    __syncthreads();
  }
  float mean = red[0] * (1.f / DD);
  __syncthreads();
  float s2 = 0.f;
  for (int d = tid; d < DD; d += 256) {
    float v = ys[d] - mean;
    s2 += v * v;
  }
  red[tid] = s2;
  __syncthreads();
  for (int off = 128; off; off >>= 1) {
    if (tid < off) red[tid] += red[tid + off];
    __syncthreads();
  }
  float rstd = rsqrtf(red[0] * (1.f / DD) + 1e-6f);
  for (int d = tid; d < DD; d += 256)
    out[(size_t)row * DD + d] = gamma[d] * ((ys[d] - mean) * rstd) + beta[d];
}

extern "C" void kernel_launch(void* const* d_in, const int* in_sizes, int n_in,
                              void* d_out, int out_size, void* d_ws, size_t ws_size,
                              hipStream_t stream) {
  const float* Qf = (const float*)d_in[0];
  const float* Cf = (const float*)d_in[1];
  const float* gamma = (const float*)d_in[2];
  const float* beta = (const float*)d_in[3];
  float* out = (float*)d_out;
  const size_t nelem = (size_t)NB * LK * DD;  // 8,388,608
  const size_t need = nelem * 2 * 2;          // Cb + Ctb (33.5 MB)
  if (ws_size >= need) {
    uint16_t* Cb = (uint16_t*)d_ws;
    uint16_t* Ctb = Cb + nelem;
    prep_kernel<<<dim3(LK / 32, DD / 32, NB), dim3(32, 8), 0, stream>>>(Cf, Cb, Ctb);
    attn_kernel<<<256, 512, 0, stream>>>(Cb, Ctb, Qf, gamma, beta, out);
  } else {
    naive_kernel<<<NB * LQ, 256, 0, stream>>>(Qf, Cf, gamma, beta, out);
  }
}